// Round 1
// baseline (2669.946 us; speedup 1.0000x reference)
//
#include <hip/hip_runtime.h>
#include <hip/hip_bf16.h>

#define N 4096
#define D 512

// ---------------- row squared-norms: one wave per row ----------------
__global__ __launch_bounds__(256) void row_norms_k(const float* __restrict__ X,
                                                   float* __restrict__ out) {
    int wave = threadIdx.x >> 6;
    int lane = threadIdx.x & 63;
    int row  = blockIdx.x * 4 + wave;
    const float* xr = X + (size_t)row * D;
    float s = 0.f;
#pragma unroll
    for (int k = 0; k < D / 64; ++k) {
        float v = xr[lane + 64 * k];
        s += v * v;
    }
#pragma unroll
    for (int off = 32; off >= 1; off >>= 1) s += __shfl_down(s, off);
    if (lane == 0) out[row] = s;
}

// ---------------- cost matrix: M = max(x2_i + y2_j - 2 * X Y^T, 0) ----------------
// fp32 tiled GEMM: 64x64 tile, 256 threads, 4x4 micro-tile per thread.
__global__ __launch_bounds__(256) void gemm_cost_k(const float* __restrict__ X,
                                                   const float* __restrict__ Y,
                                                   const float* __restrict__ x2,
                                                   const float* __restrict__ y2,
                                                   float* __restrict__ M) {
    __shared__ float As[16][68];   // [k][i], stride 68 floats (16B-aligned rows, conflict-benign)
    __shared__ float Bs[16][68];   // [k][j]
    int tid = threadIdx.x;
    int tx = tid & 15, ty = tid >> 4;
    int i0 = blockIdx.y * 64, j0 = blockIdx.x * 64;
    int lr = tid >> 2;          // 0..63 row within tile
    int lk = (tid & 3) << 2;    // 0,4,8,12

    float acc[4][4] = {{0.f, 0.f, 0.f, 0.f}, {0.f, 0.f, 0.f, 0.f},
                       {0.f, 0.f, 0.f, 0.f}, {0.f, 0.f, 0.f, 0.f}};

    for (int k0 = 0; k0 < D; k0 += 16) {
        float4 av = *(const float4*)(X + (size_t)(i0 + lr) * D + k0 + lk);
        float4 bv = *(const float4*)(Y + (size_t)(j0 + lr) * D + k0 + lk);
        As[lk + 0][lr] = av.x; As[lk + 1][lr] = av.y;
        As[lk + 2][lr] = av.z; As[lk + 3][lr] = av.w;
        Bs[lk + 0][lr] = bv.x; Bs[lk + 1][lr] = bv.y;
        Bs[lk + 2][lr] = bv.z; Bs[lk + 3][lr] = bv.w;
        __syncthreads();
#pragma unroll
        for (int k = 0; k < 16; ++k) {
            float4 a = *(const float4*)&As[k][ty * 4];
            float4 b = *(const float4*)&Bs[k][tx * 4];
            acc[0][0] += a.x * b.x; acc[0][1] += a.x * b.y; acc[0][2] += a.x * b.z; acc[0][3] += a.x * b.w;
            acc[1][0] += a.y * b.x; acc[1][1] += a.y * b.y; acc[1][2] += a.y * b.z; acc[1][3] += a.y * b.w;
            acc[2][0] += a.z * b.x; acc[2][1] += a.z * b.y; acc[2][2] += a.z * b.z; acc[2][3] += a.z * b.w;
            acc[3][0] += a.w * b.x; acc[3][1] += a.w * b.y; acc[3][2] += a.w * b.z; acc[3][3] += a.w * b.w;
        }
        __syncthreads();
    }

#pragma unroll
    for (int rr = 0; rr < 4; ++rr) {
        int i = i0 + ty * 4 + rr;
        float xi = x2[i];
        int j = j0 + tx * 4;
        float4 o;
        o.x = fmaxf(xi + y2[j + 0] - 2.f * acc[rr][0], 0.f);
        o.y = fmaxf(xi + y2[j + 1] - 2.f * acc[rr][1], 0.f);
        o.z = fmaxf(xi + y2[j + 2] - 2.f * acc[rr][2], 0.f);
        o.w = fmaxf(xi + y2[j + 3] - 2.f * acc[rr][3], 0.f);
        *(float4*)(M + (size_t)i * N + j) = o;
    }
}

// ---------------- LDS-tiled transpose ----------------
__global__ __launch_bounds__(256) void transpose_k(const float* __restrict__ in,
                                                   float* __restrict__ out) {
    __shared__ float tile[32][33];
    int bx = blockIdx.x * 32, by = blockIdx.y * 32;
    int tx = threadIdx.x, ty = threadIdx.y;  // 32 x 8
#pragma unroll
    for (int r = 0; r < 32; r += 8)
        tile[ty + r][tx] = in[(size_t)(by + ty + r) * N + bx + tx];
    __syncthreads();
#pragma unroll
    for (int r = 0; r < 32; r += 8)
        out[(size_t)(bx + ty + r) * N + by + tx] = tile[tx][ty + r];
}

// ---------------- one Sinkhorn half-step ----------------
// vout[row] = logw - LSE_j( vin[j] - Mr[row][j] )   (REG = 1)
__global__ __launch_bounds__(256) void sinkhorn_half_k(const float* __restrict__ Mr,
                                                       const float* __restrict__ vin,
                                                       float* __restrict__ vout,
                                                       float logw) {
    int row = blockIdx.x;
    const float* Mrow = Mr + (size_t)row * N;
    int t = threadIdx.x;
    float vals[16];
    float m = -3.4e38f;
#pragma unroll
    for (int k = 0; k < 16; ++k) {
        int j = t + 256 * k;
        float tv = vin[j] - Mrow[j];
        vals[k] = tv;
        m = fmaxf(m, tv);
    }
    float s = 0.f;
#pragma unroll
    for (int k = 0; k < 16; ++k) s += __expf(vals[k] - m);
    // wave-level (m,s) merge
#pragma unroll
    for (int off = 32; off >= 1; off >>= 1) {
        float mo = __shfl_down(m, off);
        float so = __shfl_down(s, off);
        float mn = fmaxf(m, mo);
        s = s * __expf(m - mn) + so * __expf(mo - mn);
        m = mn;
    }
    __shared__ float sm[4], ss[4];
    int wave = t >> 6, lane = t & 63;
    if (lane == 0) { sm[wave] = m; ss[wave] = s; }
    __syncthreads();
    if (t == 0) {
        float mm = sm[0], S = ss[0];
#pragma unroll
        for (int w = 1; w < 4; ++w) {
            float mo = sm[w];
            float mn = fmaxf(mm, mo);
            S = S * __expf(mm - mn) + ss[w] * __expf(mo - mn);
            mm = mn;
        }
        vout[row] = logw - (mm + __logf(S));
    }
}

// ---------------- final objective ----------------
// value = sum_ij [ p*(M + lp - la - lb - 1) ] + 1,  lp = f_i + g_j - M_ij, p = exp(lp)
__global__ __launch_bounds__(256) void ot_value_k(const float* __restrict__ M,
                                                  const float* __restrict__ f,
                                                  const float* __restrict__ g,
                                                  float* __restrict__ out,
                                                  float lab) {
    int row = blockIdx.x;
    const float* Mrow = M + (size_t)row * N;
    float fi = f[row];
    int t = threadIdx.x;
    float local = 0.f;
#pragma unroll
    for (int k = 0; k < 16; ++k) {
        int j = t + 256 * k;
        float mm = Mrow[j];
        float lp = fi + g[j] - mm;
        float p = __expf(lp);
        local += p * (mm + lp - lab - 1.0f);
    }
#pragma unroll
    for (int off = 32; off >= 1; off >>= 1) local += __shfl_down(local, off);
    __shared__ float ps[4];
    int wave = t >> 6, lane = t & 63;
    if (lane == 0) ps[wave] = local;
    __syncthreads();
    if (t == 0) {
        float sum = ps[0] + ps[1] + ps[2] + ps[3];
        if (row == 0) sum += 1.0f;
        atomicAdd(out, sum);
    }
}

extern "C" void kernel_launch(void* const* d_in, const int* in_sizes, int n_in,
                              void* d_out, int out_size, void* d_ws, size_t ws_size,
                              hipStream_t stream) {
    const float* src = (const float*)d_in[0];
    const float* tgt = (const float*)d_in[1];
    float* out = (float*)d_out;

    // workspace layout: M (64MB) | MT (64MB) | x2 | y2 | f | g
    float* M  = (float*)d_ws;
    float* MT = M + (size_t)N * N;
    float* x2 = MT + (size_t)N * N;
    float* y2 = x2 + N;
    float* f  = y2 + N;
    float* g  = f + N;

    const float la = -8.317766166719343f;  // -log(4096)
    const float lb = la;

    hipMemsetAsync(f, 0, 2 * N * sizeof(float), stream);  // f and g contiguous
    hipMemsetAsync(d_out, 0, sizeof(float), stream);

    row_norms_k<<<N / 4, 256, 0, stream>>>(src, x2);
    row_norms_k<<<N / 4, 256, 0, stream>>>(tgt, y2);
    gemm_cost_k<<<dim3(N / 64, N / 64), 256, 0, stream>>>(src, tgt, x2, y2, M);
    transpose_k<<<dim3(N / 32, N / 32), dim3(32, 8), 0, stream>>>(M, MT);

    for (int it = 0; it < 100; ++it) {
        sinkhorn_half_k<<<N, 256, 0, stream>>>(M,  g, f, la);
        sinkhorn_half_k<<<N, 256, 0, stream>>>(MT, f, g, lb);
    }

    ot_value_k<<<N, 256, 0, stream>>>(M, f, g, out, la + lb);
}

// Round 2
// 1703.956 us; speedup vs baseline: 1.5669x; 1.5669x over previous
//
#include <hip/hip_runtime.h>
#include <hip/hip_bf16.h>

#define N 4096
#define D 512

typedef unsigned short u16;
typedef __attribute__((ext_vector_type(8))) short short8;
typedef __attribute__((ext_vector_type(8))) unsigned short ushort8;
typedef __attribute__((ext_vector_type(4))) float fvec4;

static __device__ __forceinline__ float bf2f(unsigned short u) {
    union { unsigned int i; float f; } c;
    c.i = ((unsigned int)u) << 16;
    return c.f;
}

static __device__ __forceinline__ unsigned short f2bf(float x) {
    __hip_bfloat16 h = __float2bfloat16(x);  // RNE
    unsigned short u;
    __builtin_memcpy(&u, &h, 2);
    return u;
}

static __device__ __forceinline__ void gld_lds16(const u16* gp, u16* lp) {
    __builtin_amdgcn_global_load_lds(
        (__attribute__((address_space(1))) void*)(u16*)gp,
        (__attribute__((address_space(3))) void*)lp, 16, 0, 0);
}

// ---------------- fp32 -> bf16 convert (8 elems/thread) ----------------
__global__ __launch_bounds__(256) void f32_to_bf16_k(const float* __restrict__ in,
                                                     u16* __restrict__ out) {
    int idx = blockIdx.x * 256 + threadIdx.x;
    fvec4 a = *((const fvec4*)in + idx * 2);
    fvec4 b = *((const fvec4*)in + idx * 2 + 1);
    ushort8 o;
#pragma unroll
    for (int e = 0; e < 4; ++e) { o[e] = f2bf(a[e]); o[4 + e] = f2bf(b[e]); }
    *((ushort8*)out + idx) = o;
}

// ---------------- row squared-norms: one wave per row ----------------
__global__ __launch_bounds__(256) void row_norms_k(const float* __restrict__ X,
                                                   float* __restrict__ out) {
    int wave = threadIdx.x >> 6;
    int lane = threadIdx.x & 63;
    int row  = blockIdx.x * 4 + wave;
    const float* xr = X + (size_t)row * D;
    float s = 0.f;
#pragma unroll
    for (int k = 0; k < D / 64; ++k) {
        float v = xr[lane + 64 * k];
        s += v * v;
    }
#pragma unroll
    for (int off = 32; off >= 1; off >>= 1) s += __shfl_down(s, off);
    if (lane == 0) out[row] = s;
}

// ---------------- cost matrix via bf16 MFMA (m97 pattern) ----------------
// M[i][j] = bf16( max(x2_i + y2_j - 2 * X_i . Y_j, 0) )
// 128x128 tile, BK=32, 256 threads (4 waves in 2x2), global_load_lds width 16.
__global__ __launch_bounds__(256) void gemm_cost_bf16_k(const u16* __restrict__ A,
                                                        const u16* __restrict__ B,
                                                        const float* __restrict__ x2,
                                                        const float* __restrict__ y2,
                                                        u16* __restrict__ M) {
    __shared__ u16 As[128 * 32];  // [row][k] row-major, unpadded (global_load_lds)
    __shared__ u16 Bs[128 * 32];
    int tid = threadIdx.x;
    int wave = tid >> 6, lane = tid & 63;
    int i0 = blockIdx.y * 128, j0 = blockIdx.x * 128;
    int wr = (wave >> 1) * 64, wc = (wave & 1) * 64;

    fvec4 acc[4][4] = {};

    // staging: 4 lanes per row (4x8 bf16 = 64B), wave covers 16 rows per issue
    int srow = wave * 16 + (lane >> 2);
    int skk  = (lane & 3) * 8;
    const u16* ga0 = A + (size_t)(i0 + srow) * D + skk;
    const u16* ga1 = A + (size_t)(i0 + 64 + srow) * D + skk;
    const u16* gb0 = B + (size_t)(j0 + srow) * D + skk;
    const u16* gb1 = B + (size_t)(j0 + 64 + srow) * D + skk;
    u16* la0 = &As[(wave * 16) * 32];       // wave-uniform LDS base; HW adds lane*16B
    u16* la1 = &As[(64 + wave * 16) * 32];
    u16* lb0 = &Bs[(wave * 16) * 32];
    u16* lb1 = &Bs[(64 + wave * 16) * 32];

    int fr = lane & 15, q = lane >> 4;

    for (int k0 = 0; k0 < D; k0 += 32) {
        __syncthreads();
        gld_lds16(ga0 + k0, la0);
        gld_lds16(ga1 + k0, la1);
        gld_lds16(gb0 + k0, lb0);
        gld_lds16(gb1 + k0, lb1);
        __syncthreads();
        short8 af[4], bf[4];
#pragma unroll
        for (int t = 0; t < 4; ++t) {
            af[t] = *(const short8*)&As[(wr + t * 16 + fr) * 32 + q * 8];
            bf[t] = *(const short8*)&Bs[(wc + t * 16 + fr) * 32 + q * 8];
        }
#pragma unroll
        for (int ri = 0; ri < 4; ++ri)
#pragma unroll
            for (int ci = 0; ci < 4; ++ci)
                acc[ri][ci] = __builtin_amdgcn_mfma_f32_16x16x32_bf16(af[ri], bf[ci],
                                                                      acc[ri][ci], 0, 0, 0);
    }

    // epilogue: C/D layout col=lane&15, row=(lane>>4)*4+reg
#pragma unroll
    for (int ri = 0; ri < 4; ++ri) {
#pragma unroll
        for (int ci = 0; ci < 4; ++ci) {
            int j = j0 + wc + ci * 16 + fr;
            float yj = y2[j];
#pragma unroll
            for (int r = 0; r < 4; ++r) {
                int i = i0 + wr + ri * 16 + q * 4 + r;
                float val = fmaxf(x2[i] + yj - 2.0f * acc[ri][ci][r], 0.0f);
                M[(size_t)i * N + j] = f2bf(val);
            }
        }
    }
}

// ---------------- bf16 LDS-tiled transpose ----------------
__global__ __launch_bounds__(256) void transpose_bf16_k(const u16* __restrict__ in,
                                                        u16* __restrict__ out) {
    __shared__ u16 tile[64][66];
    int bx = blockIdx.x * 64, by = blockIdx.y * 64;
    int tx = threadIdx.x & 63, ty = threadIdx.x >> 6;
#pragma unroll
    for (int r = 0; r < 64; r += 4)
        tile[r + ty][tx] = in[(size_t)(by + r + ty) * N + bx + tx];
    __syncthreads();
#pragma unroll
    for (int r = 0; r < 64; r += 4)
        out[(size_t)(bx + r + ty) * N + by + tx] = tile[tx][r + ty];
}

// ---------------- one Sinkhorn half-step (bf16 M) ----------------
// vout[row] = logw - LSE_j( vin[j] - Mr[row][j] )
__global__ __launch_bounds__(256) void sinkhorn_half_bf16_k(const u16* __restrict__ Mr,
                                                            const float* __restrict__ vin,
                                                            float* __restrict__ vout,
                                                            float logw) {
    int row = blockIdx.x;
    const u16* Mrow = Mr + (size_t)row * N;
    int t = threadIdx.x;
    ushort8 m0 = *(const ushort8*)(Mrow + t * 8);
    ushort8 m1 = *(const ushort8*)(Mrow + 2048 + t * 8);
    fvec4 ga0 = *(const fvec4*)(vin + t * 8);
    fvec4 ga1 = *(const fvec4*)(vin + t * 8 + 4);
    fvec4 gb0 = *(const fvec4*)(vin + 2048 + t * 8);
    fvec4 gb1 = *(const fvec4*)(vin + 2048 + t * 8 + 4);
    float tv[16];
#pragma unroll
    for (int e = 0; e < 4; ++e) {
        tv[e]      = ga0[e] - bf2f(m0[e]);
        tv[4 + e]  = ga1[e] - bf2f(m0[4 + e]);
        tv[8 + e]  = gb0[e] - bf2f(m1[e]);
        tv[12 + e] = gb1[e] - bf2f(m1[4 + e]);
    }
    float m = tv[0];
#pragma unroll
    for (int e = 1; e < 16; ++e) m = fmaxf(m, tv[e]);
    float s = 0.f;
#pragma unroll
    for (int e = 0; e < 16; ++e) s += __expf(tv[e] - m);
    // wave-level (m,s) merge
#pragma unroll
    for (int off = 32; off >= 1; off >>= 1) {
        float mo = __shfl_down(m, off);
        float so = __shfl_down(s, off);
        float mn = fmaxf(m, mo);
        s = s * __expf(m - mn) + so * __expf(mo - mn);
        m = mn;
    }
    __shared__ float sm[4], ss[4];
    int wave = t >> 6, lane = t & 63;
    if (lane == 0) { sm[wave] = m; ss[wave] = s; }
    __syncthreads();
    if (t == 0) {
        float mm = sm[0], S = ss[0];
#pragma unroll
        for (int w = 1; w < 4; ++w) {
            float mo = sm[w];
            float mn = fmaxf(mm, mo);
            S = S * __expf(mm - mn) + ss[w] * __expf(mo - mn);
            mm = mn;
        }
        vout[row] = logw - (mm + __logf(S));
    }
}

// ---------------- final objective ----------------
// value = sum_ij p*(f_i + g_j - la - lb - 1) + 1,  p = exp(f_i + g_j - M_ij)
__global__ __launch_bounds__(256) void ot_value_bf16_k(const u16* __restrict__ M,
                                                       const float* __restrict__ f,
                                                       const float* __restrict__ g,
                                                       float* __restrict__ out,
                                                       float lab) {
    int row = blockIdx.x;
    const u16* Mrow = M + (size_t)row * N;
    float fi = f[row];
    int t = threadIdx.x;
    ushort8 m0 = *(const ushort8*)(Mrow + t * 8);
    ushort8 m1 = *(const ushort8*)(Mrow + 2048 + t * 8);
    fvec4 ga0 = *(const fvec4*)(g + t * 8);
    fvec4 ga1 = *(const fvec4*)(g + t * 8 + 4);
    fvec4 gb0 = *(const fvec4*)(g + 2048 + t * 8);
    fvec4 gb1 = *(const fvec4*)(g + 2048 + t * 8 + 4);
    float local = 0.f;
#pragma unroll
    for (int e = 0; e < 4; ++e) {
        float mv, lp;
        mv = bf2f(m0[e]);     lp = fi + ga0[e] - mv; local += __expf(lp) * (mv + lp - lab - 1.0f);
        mv = bf2f(m0[4 + e]); lp = fi + ga1[e] - mv; local += __expf(lp) * (mv + lp - lab - 1.0f);
        mv = bf2f(m1[e]);     lp = fi + gb0[e] - mv; local += __expf(lp) * (mv + lp - lab - 1.0f);
        mv = bf2f(m1[4 + e]); lp = fi + gb1[e] - mv; local += __expf(lp) * (mv + lp - lab - 1.0f);
    }
#pragma unroll
    for (int off = 32; off >= 1; off >>= 1) local += __shfl_down(local, off);
    __shared__ float ps[4];
    int wave = t >> 6, lane = t & 63;
    if (lane == 0) ps[wave] = local;
    __syncthreads();
    if (t == 0) {
        float sum = ps[0] + ps[1] + ps[2] + ps[3];
        if (row == 0) sum += 1.0f;
        atomicAdd(out, sum);
    }
}

extern "C" void kernel_launch(void* const* d_in, const int* in_sizes, int n_in,
                              void* d_out, int out_size, void* d_ws, size_t ws_size,
                              hipStream_t stream) {
    const float* src = (const float*)d_in[0];
    const float* tgt = (const float*)d_in[1];
    float* out = (float*)d_out;

    // workspace layout: Mb (32MB) | MTb (32MB) | Xb (4MB) | Yb (4MB) | x2 | y2 | f | g
    u16* Mb  = (u16*)d_ws;
    u16* MTb = Mb + (size_t)N * N;
    u16* Xb  = MTb + (size_t)N * N;
    u16* Yb  = Xb + (size_t)N * D;
    float* x2 = (float*)(Yb + (size_t)N * D);
    float* y2 = x2 + N;
    float* f  = y2 + N;
    float* g  = f + N;

    const float la = -8.317766166719343f;  // -log(4096)
    const float lb = la;

    hipMemsetAsync(f, 0, 2 * N * sizeof(float), stream);  // f and g contiguous
    hipMemsetAsync(d_out, 0, sizeof(float), stream);

    f32_to_bf16_k<<<N * D / (256 * 8), 256, 0, stream>>>(src, Xb);
    f32_to_bf16_k<<<N * D / (256 * 8), 256, 0, stream>>>(tgt, Yb);
    row_norms_k<<<N / 4, 256, 0, stream>>>(src, x2);
    row_norms_k<<<N / 4, 256, 0, stream>>>(tgt, y2);
    gemm_cost_bf16_k<<<dim3(N / 128, N / 128), 256, 0, stream>>>(Xb, Yb, x2, y2, Mb);
    transpose_bf16_k<<<dim3(N / 64, N / 64), 256, 0, stream>>>(Mb, MTb);

    for (int it = 0; it < 100; ++it) {
        sinkhorn_half_bf16_k<<<N, 256, 0, stream>>>(Mb,  g, f, la);
        sinkhorn_half_bf16_k<<<N, 256, 0, stream>>>(MTb, f, g, lb);
    }

    ot_value_bf16_k<<<N, 256, 0, stream>>>(Mb, f, g, out, la + lb);
}